// Round 4
// baseline (599.571 us; speedup 1.0000x reference)
//
#include <hip/hip_runtime.h>
#include <hip/hip_bf16.h>
#include <math.h>

#define BB 2
#define DIM 384
#define HID 384
#define HW 65536

typedef short s16x8 __attribute__((ext_vector_type(8)));
typedef short s16x4 __attribute__((ext_vector_type(4)));
typedef __bf16 bf16x8 __attribute__((ext_vector_type(8)));
typedef float f32x4 __attribute__((ext_vector_type(4)));

__device__ inline short f2b(float f) {
    __hip_bfloat16 h = __float2bfloat16(f);
    return __builtin_bit_cast(short, h);
}
__device__ inline float b2f(short s) {
    return __bfloat162float(__builtin_bit_cast(__hip_bfloat16, s));
}

__device__ inline void gl_lds16(const short* g, short* l) {
    __builtin_amdgcn_global_load_lds(
        (const __attribute__((address_space(1))) unsigned int*)g,
        (__attribute__((address_space(3))) unsigned int*)l, 16, 0, 0);
}

// ---------------------------------------------------------------------------
// R: 64x64 2D-Hartley (cas) basis, bf16. Self-inverse: R*R = 64*I.
// ---------------------------------------------------------------------------
__global__ void k_prepR(short* __restrict__ Rb) {
    int idx = blockIdx.x * 256 + threadIdx.x;
    int j = idx >> 6, k = idx & 63;
    const float cas[8] = {1.f, 1.41421356237f, 1.f, 0.f, -1.f, -1.41421356237f, -1.f, 0.f};
    int t = ((j >> 3) * (k >> 3) + (j & 7) * (k & 7)) & 7;
    Rb[idx] = f2b(cas[t]);
}

// ---------------------------------------------------------------------------
// Dt[j][c] f32: Hartley eigenvalue of the per-channel filter (incl. 1/64).
// d[p,q] = s[p,q] (q in 1..3); mirror for q in 5..7; symmetrized avg q in {0,4}.
// ---------------------------------------------------------------------------
__global__ void k_prepD(const float* __restrict__ F, float* __restrict__ Dt) {
    int idx = blockIdx.x * 256 + threadIdx.x;    // 96 blocks x 256 = 384*64
    int c = idx >> 6, j = idx & 63;
    int a = j >> 3, q = j & 7;
    float d;
    if (q >= 1 && q <= 3)
        d = F[c * 40 + a * 5 + q];
    else if (q >= 5)
        d = F[c * 40 + ((8 - a) & 7) * 5 + (8 - q)];
    else
        d = 0.5f * (F[c * 40 + a * 5 + q] + F[c * 40 + ((8 - a) & 7) * 5 + q]);
    Dt[j * 384 + c] = d * (1.f / 64.f);
}

__global__ void k_cvtw(const float* __restrict__ in, short* __restrict__ out, int n) {
    int i = blockIdx.x * 256 + threadIdx.x;
    if (i < n) out[i] = f2b(in[i]);
}

// ---------------------------------------------------------------------------
// x [b][c][hw] fp32  ->  Xt [b][hw][384] bf16
// XOR-swizzled LDS transpose: phys col = s ^ ((c>>3)<<3)  (2-way max, free)
// ---------------------------------------------------------------------------
__global__ __launch_bounds__(256) void k_cvtx(const float* __restrict__ X, short* __restrict__ Xt) {
    int hw0 = blockIdx.x * 64, c0 = blockIdx.y * 64, b = blockIdx.z;
    __shared__ __align__(16) short S[64 * 64];
    int t = threadIdx.x;
    const float* Xb = X + ((size_t)(b * DIM) << 16);
    short* Xtb = Xt + (size_t)b * HW * DIM;
#pragma unroll
    for (int p = 0; p < 2; ++p) {
        int row = p * 32 + (t >> 3), sb = t & 7;
        const float* src = &Xb[((size_t)(c0 + row) << 16) + hw0 + sb * 8];
        float4 a = *(const float4*)src;
        float4 bq = *(const float4*)(src + 4);
        s16x8 v;
        v[0] = f2b(a.x);  v[1] = f2b(a.y);  v[2] = f2b(a.z);  v[3] = f2b(a.w);
        v[4] = f2b(bq.x); v[5] = f2b(bq.y); v[6] = f2b(bq.z); v[7] = f2b(bq.w);
        *(s16x8*)&S[row * 64 + ((sb ^ (row >> 3)) << 3)] = v;
    }
    __syncthreads();
#pragma unroll
    for (int p = 0; p < 2; ++p) {
        int row = p * 32 + (t >> 3), ch = t & 7;
        s16x8 v;
#pragma unroll
        for (int j = 0; j < 8; ++j)
            v[j] = S[(ch * 8 + j) * 64 + (row ^ (ch << 3))];
        *(s16x8*)&Xtb[(size_t)(hw0 + row) * DIM + c0 + ch * 8] = v;
    }
}

// ---------------------------------------------------------------------------
// Fused GEMM1 + circular conv via Hartley: T = R*diag(d_c)*R applied to the
// acc tile in-LDS (two K=64 MFMA stages), output written spatial to T.
// Grid x = 1536 flattened (512 spatial x 3 m), m fastest, XCD-chunk remapped.
// ---------------------------------------------------------------------------
__global__ __launch_bounds__(256) void k_gemm1c(const short* __restrict__ A,
                                                const short* __restrict__ Bt,
                                                const short* __restrict__ Rb,
                                                const float* __restrict__ Dt,
                                                short* __restrict__ T) {
    __shared__ __align__(16) short SH[17408 + 4096]; // As|Bs (8192), Ep alias 128x136; Rs at +17408
    short* As = SH;
    short* Bs = SH + 4096;
    short* Rs = SH + 17408;
    int d = blockIdx.x;
    int wg = (d & 7) * 192 + (d >> 3);     // bijective XCD chunk remap (1536 % 8 == 0)
    int m0 = (wg % 3) * 128;
    int tx = wg / 3;
    int h0 = (tx >> 4) * 8;
    int w0 = (tx & 15) * 16;
    int b  = blockIdx.z;
    const short* Bz = Bt + (size_t)b * HW * DIM;
    int tid = threadIdx.x;
    int lane = tid & 63, w = tid >> 6;
    int wr = w >> 1, wc = w & 1;
    int lm = lane & 15, quad = lane >> 4;

    // stage Hartley basis R (swizzled source -> linear LDS dest)
    {
        int j0 = tid >> 3, kb0 = tid & 7;
        gl_lds16(Rb + j0 * 64 + ((kb0 ^ (j0 & 7)) << 3), Rs + tid * 8);
        int t2 = tid + 256;
        int j1 = t2 >> 3, kb1 = t2 & 7;
        gl_lds16(Rb + j1 * 64 + ((kb1 ^ (j1 & 7)) << 3), Rs + t2 * 8);
    }

    f32x4 acc[4][4];
#pragma unroll
    for (int i = 0; i < 4; ++i)
#pragma unroll
        for (int j = 0; j < 4; ++j) acc[i][j] = 0.f;

    int srow = tid >> 2, sseg = tid & 3;
    int pu = srow >> 3, pv = srow & 7;
    int p1 = ((h0 + pu) << 8) + w0 + pv;       // pat 0
    int p2 = p1 + 8;                           // pat 1
    for (int k0 = 0; k0 < DIM; k0 += 32) {
        gl_lds16(A + (size_t)(m0 + srow) * DIM + k0 + sseg * 8, As + tid * 8);
        gl_lds16(A + (size_t)(m0 + 64 + srow) * DIM + k0 + sseg * 8, As + (tid + 256) * 8);
        gl_lds16(Bz + (size_t)p1 * DIM + k0 + sseg * 8, Bs + tid * 8);
        gl_lds16(Bz + (size_t)p2 * DIM + k0 + sseg * 8, Bs + (tid + 256) * 8);
        __syncthreads();
        bf16x8 af[4], bfr[4];
#pragma unroll
        for (int i = 0; i < 4; ++i)
            af[i] = __builtin_bit_cast(bf16x8, *(const s16x8*)&As[(wr * 64 + i * 16 + lm) * 32 + quad * 8]);
#pragma unroll
        for (int j = 0; j < 4; ++j)
            bfr[j] = __builtin_bit_cast(bf16x8, *(const s16x8*)&Bs[(wc * 64 + j * 16 + lm) * 32 + quad * 8]);
#pragma unroll
        for (int i = 0; i < 4; ++i)
#pragma unroll
            for (int j = 0; j < 4; ++j)
                acc[i][j] = __builtin_amdgcn_mfma_f32_16x16x32_bf16(af[i], bfr[j], acc[i][j], 0, 0, 0);
        __syncthreads();
    }
    // E tile (bf16) -> Ep[ch][pat*64+uv], stride 136
#pragma unroll
    for (int i = 0; i < 4; ++i)
#pragma unroll
        for (int j = 0; j < 4; ++j)
#pragma unroll
            for (int r = 0; r < 4; ++r)
                SH[(wr * 64 + i * 16 + quad * 4 + r) * 136 + wc * 64 + j * 16 + lm] =
                    f2b(acc[i][j][r]);
    __syncthreads();

    // ---- stage 1: Y = Hartley(E) along uv (K=64), then scale by Dt[j][ch]
    f32x4 acc2[4][4];
#pragma unroll
    for (int i = 0; i < 4; ++i)
#pragma unroll
        for (int j = 0; j < 4; ++j) acc2[i][j] = 0.f;
#pragma unroll
    for (int ks = 0; ks < 2; ++ks) {
        bf16x8 af[4], bfr[4];
#pragma unroll
        for (int i = 0; i < 4; ++i)
            af[i] = __builtin_bit_cast(bf16x8,
                *(const s16x8*)&SH[(wr * 64 + i * 16 + lm) * 136 + wc * 64 + ks * 32 + quad * 8]);
#pragma unroll
        for (int jf = 0; jf < 4; ++jf)
            bfr[jf] = __builtin_bit_cast(bf16x8,
                *(const s16x8*)&Rs[(jf * 16 + lm) * 64 + (((ks * 4 + quad) ^ (lm & 7)) << 3)]);
#pragma unroll
        for (int i = 0; i < 4; ++i)
#pragma unroll
            for (int jf = 0; jf < 4; ++jf)
                acc2[i][jf] = __builtin_amdgcn_mfma_f32_16x16x32_bf16(af[i], bfr[jf], acc2[i][jf], 0, 0, 0);
    }
#pragma unroll
    for (int i = 0; i < 4; ++i)
#pragma unroll
        for (int jf = 0; jf < 4; ++jf) {
            int j = jf * 16 + lm;
            float4 dv = *(const float4*)&Dt[j * 384 + m0 + wr * 64 + i * 16 + quad * 4];
            acc2[i][jf][0] *= dv.x; acc2[i][jf][1] *= dv.y;
            acc2[i][jf][2] *= dv.z; acc2[i][jf][3] *= dv.w;
        }
    __syncthreads();   // all Ep reads done
    // Y -> Ep (bf16)
#pragma unroll
    for (int i = 0; i < 4; ++i)
#pragma unroll
        for (int jf = 0; jf < 4; ++jf)
#pragma unroll
            for (int r = 0; r < 4; ++r)
                SH[(wr * 64 + i * 16 + quad * 4 + r) * 136 + wc * 64 + jf * 16 + lm] =
                    f2b(acc2[i][jf][r]);
    __syncthreads();

    // ---- stage 2: T = Hartley(Y) along j (K=64)  (1/64 already folded in Dt)
    f32x4 acc3[4][4];
#pragma unroll
    for (int i = 0; i < 4; ++i)
#pragma unroll
        for (int j = 0; j < 4; ++j) acc3[i][j] = 0.f;
#pragma unroll
    for (int ks = 0; ks < 2; ++ks) {
        bf16x8 af[4], bfr[4];
#pragma unroll
        for (int i = 0; i < 4; ++i)
            af[i] = __builtin_bit_cast(bf16x8,
                *(const s16x8*)&SH[(wr * 64 + i * 16 + lm) * 136 + wc * 64 + ks * 32 + quad * 8]);
#pragma unroll
        for (int uf = 0; uf < 4; ++uf)
            bfr[uf] = __builtin_bit_cast(bf16x8,
                *(const s16x8*)&Rs[(uf * 16 + lm) * 64 + (((ks * 4 + quad) ^ (lm & 7)) << 3)]);
#pragma unroll
        for (int i = 0; i < 4; ++i)
#pragma unroll
            for (int uf = 0; uf < 4; ++uf)
                acc3[i][uf] = __builtin_amdgcn_mfma_f32_16x16x32_bf16(af[i], bfr[uf], acc3[i][uf], 0, 0, 0);
    }
    __syncthreads();   // all Y reads done
    // T tile -> Ep (bf16)
#pragma unroll
    for (int i = 0; i < 4; ++i)
#pragma unroll
        for (int uf = 0; uf < 4; ++uf)
#pragma unroll
            for (int r = 0; r < 4; ++r)
                SH[(wr * 64 + i * 16 + quad * 4 + r) * 136 + wc * 64 + uf * 16 + lm] =
                    f2b(acc3[i][uf][r]);
    __syncthreads();
    // spatial write: T[c][h0+u][w0 + pat*8 + v]
#pragma unroll
    for (int kq = 0; kq < 8; ++kq) {
        int idx = kq * 256 + tid;
        int pat = idx & 1, ch = (idx >> 1) & 127, u = idx >> 8;
        s16x8 vv = *(const s16x8*)&SH[ch * 136 + pat * 64 + u * 8];
        *(s16x8*)&T[(((size_t)(b * HID + m0 + ch)) << 16) + ((h0 + u) << 8) + w0 + pat * 8] = vv;
    }
}

// ---------------------------------------------------------------------------
// Fused depthwise 3x3 + gelu-gate + transpose: T bf16 spatial -> Gt k-blocked
// Gt: [b][kseg=24][hw][8ch]. 8 channel-pairs per block, 64x16 spatial tile.
// ---------------------------------------------------------------------------
__global__ __launch_bounds__(256) void k_dwgt(const short* __restrict__ Y,
                                              const float* __restrict__ Wdw,
                                              short* __restrict__ Gt) {
    int bz = blockIdx.z;                 // b*24 + cg
    int b  = bz / 24;
    int cg = bz % 24;
    int c0 = cg * 8;
    int h0 = blockIdx.y * 16, w0 = blockIdx.x * 64;
    __shared__ __align__(16) short S[16][18][80];   // 46080 B
    __shared__ float sw[16][9];
    int tid = threadIdx.x;
    if (tid < 144) {
        int p = tid / 9, j = tid % 9;
        int ch = (p < 8) ? (c0 + p) : (c0 + p - 8 + 192);
        sw[p][j] = Wdw[ch * 9 + j];
    }
    for (int t = tid; t < 2880; t += 256) {
        int v = t % 10, r = (t / 10) % 18, p = t / 180;
        int gh = h0 + r - 1;
        int gw = w0 + v * 8 - 8;
        int ch = (p < 8) ? (c0 + p) : (c0 + p - 8 + 192);
        s16x8 val = {0, 0, 0, 0, 0, 0, 0, 0};
        if (gh >= 0 && gh < 256 && gw >= 0 && gw <= 248)
            val = *(const s16x8*)&Y[((size_t)(b * HID + ch) << 16) + (gh << 8) + gw];
        *(s16x8*)&S[p][r][v * 8] = val;
    }
    __syncthreads();
    s16x8 ov[4];
#pragma unroll
    for (int it = 0; it < 4; ++it) {
        int idx = it * 256 + tid;
        int p = idx >> 7, run = idx & 127;
        int r = run >> 3, c8 = (run & 7) * 8;
        float z1[8], z2[8];
#pragma unroll
        for (int k = 0; k < 8; ++k) { z1[k] = 0.f; z2[k] = 0.f; }
#pragma unroll
        for (int i = 0; i < 3; ++i) {
            {
                s16x4 wv[4];
#pragma unroll
                for (int q = 0; q < 4; ++q) wv[q] = *(const s16x4*)&S[p][r + i][c8 + 4 + q * 4];
                float fv[10];
#pragma unroll
                for (int q = 0; q < 10; ++q) fv[q] = b2f(wv[(q + 3) >> 2][(q + 3) & 3]);
#pragma unroll
                for (int j = 0; j < 3; ++j) {
                    float wgt = sw[p][i * 3 + j];
#pragma unroll
                    for (int k = 0; k < 8; ++k) z1[k] += fv[k + j] * wgt;
                }
            }
            {
                s16x4 wv[4];
#pragma unroll
                for (int q = 0; q < 4; ++q) wv[q] = *(const s16x4*)&S[p + 8][r + i][c8 + 4 + q * 4];
                float fv[10];
#pragma unroll
                for (int q = 0; q < 10; ++q) fv[q] = b2f(wv[(q + 3) >> 2][(q + 3) & 3]);
#pragma unroll
                for (int j = 0; j < 3; ++j) {
                    float wgt = sw[p + 8][i * 3 + j];
#pragma unroll
                    for (int k = 0; k < 8; ++k) z2[k] += fv[k + j] * wgt;
                }
            }
        }
#pragma unroll
        for (int k = 0; k < 8; ++k) {
            float g = 0.5f * z1[k] * (1.f + erff(z1[k] * 0.70710678118654752f));
            ov[it][k] = f2b(g * z2[k]);
        }
    }
    __syncthreads();
    short* Ob = (short*)S;
#pragma unroll
    for (int it = 0; it < 4; ++it) {
        int idx = it * 256 + tid;
        int p = idx >> 7, run = idx & 127;
        int pos = (run >> 3) * 64 + (run & 7) * 8;
#pragma unroll
        for (int k = 0; k < 8; ++k)
            Ob[(pos + k) * 9 + p] = ov[it][k];
    }
    __syncthreads();
    short* Gb = Gt + (((size_t)(b * 24 + cg)) << 16) * 8;
#pragma unroll
    for (int it = 0; it < 4; ++it) {
        int pos = it * 256 + tid;
        int r = pos >> 6, cl = pos & 63;
        s16x8 v;
#pragma unroll
        for (int k = 0; k < 8; ++k) v[k] = Ob[pos * 9 + k];
        *(s16x8*)&Gb[(size_t)(((h0 + r) << 8) + w0 + cl) * 8] = v;
    }
}

// ---------------------------------------------------------------------------
// MFMA bf16 GEMM2: C[z][m][n] = sum_k A[m][k] * Gt_blk[z][k/8][n][k%8]
// Grid x = 1536 flattened (512 n x 3 m), m fastest, XCD-chunk remapped.
// ---------------------------------------------------------------------------
__global__ __launch_bounds__(256) void k_gemm_bf16(const short* __restrict__ A,
                                                   const short* __restrict__ Bt,
                                                   float* __restrict__ C,
                                                   int N, int K) {
    __shared__ __align__(16) short As[128 * 32];
    __shared__ __align__(16) short Bs[128 * 32];
    const short* Bz = Bt + (size_t)blockIdx.z * (size_t)N * K;
    float* Cz = C + (size_t)blockIdx.z * (size_t)384 * N;
    int d = blockIdx.x;
    int wg = (d & 7) * 192 + (d >> 3);     // bijective XCD chunk remap
    int m0 = (wg % 3) * 128;
    int n0 = (wg / 3) * 128;
    int tid = threadIdx.x;
    int lane = tid & 63, w = tid >> 6;
    int wr = w >> 1, wc = w & 1;
    int lm = lane & 15, quad = lane >> 4;

    f32x4 acc[4][4];
#pragma unroll
    for (int i = 0; i < 4; ++i)
#pragma unroll
        for (int j = 0; j < 4; ++j) acc[i][j] = 0.f;

    int srow = tid >> 2, sseg = tid & 3;
    for (int k0 = 0; k0 < K; k0 += 32) {
        gl_lds16(A + (size_t)(m0 + srow) * K + k0 + sseg * 8, As + tid * 8);
        gl_lds16(A + (size_t)(m0 + 64 + srow) * K + k0 + sseg * 8, As + (tid + 256) * 8);
        gl_lds16(Bz + ((size_t)((k0 >> 3) + sseg) * HW + n0 + srow) * 8, Bs + tid * 8);
        gl_lds16(Bz + ((size_t)((k0 >> 3) + sseg) * HW + n0 + 64 + srow) * 8, Bs + (tid + 256) * 8);
        __syncthreads();
        bf16x8 af[4], bfr[4];
#pragma unroll
        for (int i = 0; i < 4; ++i)
            af[i] = __builtin_bit_cast(bf16x8, *(const s16x8*)&As[(wr * 64 + i * 16 + lm) * 32 + quad * 8]);
#pragma unroll
        for (int j = 0; j < 4; ++j)
            bfr[j] = __builtin_bit_cast(bf16x8, *(const s16x8*)&Bs[(wc * 64 + j * 16 + lm) * 32 + quad * 8]);
#pragma unroll
        for (int i = 0; i < 4; ++i)
#pragma unroll
            for (int j = 0; j < 4; ++j)
                acc[i][j] = __builtin_amdgcn_mfma_f32_16x16x32_bf16(af[i], bfr[j], acc[i][j], 0, 0, 0);
        __syncthreads();
    }
#pragma unroll
    for (int i = 0; i < 4; ++i) {
        int r0 = m0 + wr * 64 + i * 16 + quad * 4;
#pragma unroll
        for (int j = 0; j < 4; ++j) {
            int cidx = n0 + wc * 64 + j * 16 + lm;
#pragma unroll
            for (int r = 0; r < 4; ++r)
                Cz[(size_t)(r0 + r) * N + cidx] = acc[i][j][r];
        }
    }
}

// ---------------------------------------------------------------------------
extern "C" void kernel_launch(void* const* d_in, const int* in_sizes, int n_in,
                              void* d_out, int out_size, void* d_ws, size_t ws_size,
                              hipStream_t stream) {
    const float* x     = (const float*)d_in[0];
    const float* ff    = (const float*)d_in[1];
    const float* w_in  = (const float*)d_in[2];
    const float* w_dw  = (const float*)d_in[3];
    const float* w_out = (const float*)d_in[4];
    float* out = (float*)d_out;

    char* ws = (char*)d_ws;
    float* Dt   = (float*)ws;                                    // 98304 B
    short* wbin = (short*)(ws + 98304);                          // 294912 B
    short* wbout = (short*)(ws + 393216);                        // 147456 B
    short* Rbuf = (short*)(ws + 540672);                         // 8192 B
    short* bufA = (short*)(ws + 548864);                         // 100663296 B: Xt, then Gt
    short* bufB = (short*)(ws + 548864 + (size_t)100663296);     // 100663296 B: T
    short* Gt = bufA;

    k_prepR<<<16, 256, 0, stream>>>(Rbuf);
    k_prepD<<<96, 256, 0, stream>>>(ff, Dt);
    k_cvtw<<<(DIM * DIM + 255) / 256, 256, 0, stream>>>(w_in, wbin, DIM * DIM);
    k_cvtw<<<(DIM * 192 + 255) / 256, 256, 0, stream>>>(w_out, wbout, DIM * 192);
    k_cvtx<<<dim3(HW / 64, DIM / 64, BB), 256, 0, stream>>>(x, bufA);

    // fused GEMM1 + Hartley-domain circular conv -> T bf16 spatial (bufB)
    k_gemm1c<<<dim3(1536, 1, BB), 256, 0, stream>>>(wbin, bufA, Rbuf, Dt, bufB);

    // fused depthwise 3x3 + gelu-gate + transpose -> Gt k-blocked (bufA; Xt dead)
    k_dwgt<<<dim3(4, 16, BB * 24), 256, 0, stream>>>(bufB, w_dw, Gt);

    // GEMM2: out = w_out @ g  (M=384, N=65536/batch, K=192)
    k_gemm_bf16<<<dim3(1536, 1, BB), 256, 0, stream>>>(wbout, Gt, out, HW, 192);
}

// Round 5
// 585.666 us; speedup vs baseline: 1.0237x; 1.0237x over previous
//
#include <hip/hip_runtime.h>
#include <hip/hip_bf16.h>
#include <math.h>

#define BB 2
#define DIM 384
#define HID 384
#define HW 65536

typedef short s16x8 __attribute__((ext_vector_type(8)));
typedef short s16x4 __attribute__((ext_vector_type(4)));
typedef __bf16 bf16x8 __attribute__((ext_vector_type(8)));
typedef float f32x4 __attribute__((ext_vector_type(4)));

__device__ inline short f2b(float f) {
    __hip_bfloat16 h = __float2bfloat16(f);
    return __builtin_bit_cast(short, h);
}
__device__ inline float b2f(short s) {
    return __bfloat162float(__builtin_bit_cast(__hip_bfloat16, s));
}

__device__ inline void gl_lds16(const short* g, short* l) {
    __builtin_amdgcn_global_load_lds(
        (const __attribute__((address_space(1))) unsigned int*)g,
        (__attribute__((address_space(3))) unsigned int*)l, 16, 0, 0);
}

// ---------------------------------------------------------------------------
// One prep kernel: wbin (147456), wbout (73728), Dt (24576), Rb (4096).
// ---------------------------------------------------------------------------
__global__ void k_prep(const float* __restrict__ w_in, const float* __restrict__ w_out,
                       const float* __restrict__ F,
                       short* __restrict__ wbin, short* __restrict__ wbout,
                       float* __restrict__ Dt, short* __restrict__ Rb) {
    int i = blockIdx.x * 256 + threadIdx.x;
    if (i < 147456) { wbin[i] = f2b(w_in[i]); return; }
    i -= 147456;
    if (i < 73728) { wbout[i] = f2b(w_out[i]); return; }
    i -= 73728;
    if (i < 24576) {
        // Dt[j][c]: Hartley eigenvalue of per-channel filter (incl. 1/64)
        int c = i >> 6, j = i & 63;
        int a = j >> 3, q = j & 7;
        float d;
        if (q >= 1 && q <= 3)
            d = F[c * 40 + a * 5 + q];
        else if (q >= 5)
            d = F[c * 40 + ((8 - a) & 7) * 5 + (8 - q)];
        else
            d = 0.5f * (F[c * 40 + a * 5 + q] + F[c * 40 + ((8 - a) & 7) * 5 + q]);
        Dt[j * 384 + c] = d * (1.f / 64.f);
        return;
    }
    i -= 24576;
    if (i < 4096) {
        // R: 64x64 2D-Hartley (cas) basis, bf16. Symmetric, R*R = 64*I.
        int j = i >> 6, k = i & 63;
        const float cas[8] = {1.f, 1.41421356237f, 1.f, 0.f, -1.f, -1.41421356237f, -1.f, 0.f};
        int t = ((j >> 3) * (k >> 3) + (j & 7) * (k & 7)) & 7;
        Rb[i] = f2b(cas[t]);
    }
}

// ---------------------------------------------------------------------------
// x [b][c][hw] fp32  ->  Xt [b][hw][384] bf16
// XOR-swizzled LDS transpose: phys col = s ^ ((c>>3)<<3)  (2-way max, free)
// ---------------------------------------------------------------------------
__global__ __launch_bounds__(256) void k_cvtx(const float* __restrict__ X, short* __restrict__ Xt) {
    int hw0 = blockIdx.x * 64, c0 = blockIdx.y * 64, b = blockIdx.z;
    __shared__ __align__(16) short S[64 * 64];
    int t = threadIdx.x;
    const float* Xb = X + ((size_t)(b * DIM) << 16);
    short* Xtb = Xt + (size_t)b * HW * DIM;
#pragma unroll
    for (int p = 0; p < 2; ++p) {
        int row = p * 32 + (t >> 3), sb = t & 7;
        const float* src = &Xb[((size_t)(c0 + row) << 16) + hw0 + sb * 8];
        float4 a = *(const float4*)src;
        float4 bq = *(const float4*)(src + 4);
        s16x8 v;
        v[0] = f2b(a.x);  v[1] = f2b(a.y);  v[2] = f2b(a.z);  v[3] = f2b(a.w);
        v[4] = f2b(bq.x); v[5] = f2b(bq.y); v[6] = f2b(bq.z); v[7] = f2b(bq.w);
        *(s16x8*)&S[row * 64 + ((sb ^ (row >> 3)) << 3)] = v;
    }
    __syncthreads();
#pragma unroll
    for (int p = 0; p < 2; ++p) {
        int row = p * 32 + (t >> 3), ch = t & 7;
        s16x8 v;
#pragma unroll
        for (int j = 0; j < 8; ++j)
            v[j] = S[(ch * 8 + j) * 64 + (row ^ (ch << 3))];
        *(s16x8*)&Xtb[(size_t)(hw0 + row) * DIM + c0 + ch * 8] = v;
    }
}

// ---------------------------------------------------------------------------
// Fused GEMM1 + circular conv via Hartley: T = R*diag(d_c)*R on the acc tile.
// All epilogue stages are warp-quadrant-local in Ep -> only ONE barrier
// (before the cross-warp global write). Output T is PATCH-MAJOR:
// T[b][ch][pid][uv], so each Ep row writes as a contiguous 256B run.
// ---------------------------------------------------------------------------
__global__ __launch_bounds__(256) void k_gemm1c(const short* __restrict__ A,
                                                const short* __restrict__ Bt,
                                                const short* __restrict__ Rb,
                                                const float* __restrict__ Dt,
                                                short* __restrict__ T) {
    __shared__ __align__(16) short SH[17408 + 4096]; // As|Bs (8192), Ep alias 128x136; Rs at +17408
    short* As = SH;
    short* Bs = SH + 4096;
    short* Rs = SH + 17408;
    int d = blockIdx.x;
    int wg = (d & 7) * 192 + (d >> 3);     // bijective XCD chunk remap (1536 % 8 == 0)
    int m0 = (wg % 3) * 128;
    int tx = wg / 3;
    int h0 = (tx >> 4) * 8;
    int w0 = (tx & 15) * 16;
    int b  = blockIdx.z;
    const short* Bz = Bt + (size_t)b * HW * DIM;
    int tid = threadIdx.x;
    int lane = tid & 63, w = tid >> 6;
    int wr = w >> 1, wc = w & 1;
    int lm = lane & 15, quad = lane >> 4;

    // stage Hartley basis R (swizzled source -> linear LDS dest)
    {
        int j0 = tid >> 3, kb0 = tid & 7;
        gl_lds16(Rb + j0 * 64 + ((kb0 ^ (j0 & 7)) << 3), Rs + tid * 8);
        int t2 = tid + 256;
        int j1 = t2 >> 3, kb1 = t2 & 7;
        gl_lds16(Rb + j1 * 64 + ((kb1 ^ (j1 & 7)) << 3), Rs + t2 * 8);
    }

    f32x4 acc[4][4];
#pragma unroll
    for (int i = 0; i < 4; ++i)
#pragma unroll
        for (int j = 0; j < 4; ++j) acc[i][j] = 0.f;

    int srow = tid >> 2, sseg = tid & 3;
    int pu = srow >> 3, pv = srow & 7;
    int p1 = ((h0 + pu) << 8) + w0 + pv;       // pat 0
    int p2 = p1 + 8;                           // pat 1
    for (int k0 = 0; k0 < DIM; k0 += 32) {
        gl_lds16(A + (size_t)(m0 + srow) * DIM + k0 + sseg * 8, As + tid * 8);
        gl_lds16(A + (size_t)(m0 + 64 + srow) * DIM + k0 + sseg * 8, As + (tid + 256) * 8);
        gl_lds16(Bz + (size_t)p1 * DIM + k0 + sseg * 8, Bs + tid * 8);
        gl_lds16(Bz + (size_t)p2 * DIM + k0 + sseg * 8, Bs + (tid + 256) * 8);
        __syncthreads();
        bf16x8 af[4], bfr[4];
#pragma unroll
        for (int i = 0; i < 4; ++i)
            af[i] = __builtin_bit_cast(bf16x8, *(const s16x8*)&As[(wr * 64 + i * 16 + lm) * 32 + quad * 8]);
#pragma unroll
        for (int j = 0; j < 4; ++j)
            bfr[j] = __builtin_bit_cast(bf16x8, *(const s16x8*)&Bs[(wc * 64 + j * 16 + lm) * 32 + quad * 8]);
#pragma unroll
        for (int i = 0; i < 4; ++i)
#pragma unroll
            for (int j = 0; j < 4; ++j)
                acc[i][j] = __builtin_amdgcn_mfma_f32_16x16x32_bf16(af[i], bfr[j], acc[i][j], 0, 0, 0);
        __syncthreads();
    }
    // ---- E tile (bf16) -> Ep[ch][pat*64+uv], stride 136. Quadrant-local.
#pragma unroll
    for (int i = 0; i < 4; ++i)
#pragma unroll
        for (int j = 0; j < 4; ++j)
#pragma unroll
            for (int r = 0; r < 4; ++r)
                SH[(wr * 64 + i * 16 + quad * 4 + r) * 136 + wc * 64 + j * 16 + lm] =
                    f2b(acc[i][j][r]);
    // (no barrier: stage1 reads only this warp's quadrant; same-wave DS is in-order)

    // ---- stage 1: Y = E x R (contract uv within pat=wc), scale by Dt[j][ch]
    f32x4 acc2[4][4];
#pragma unroll
    for (int i = 0; i < 4; ++i)
#pragma unroll
        for (int j = 0; j < 4; ++j) acc2[i][j] = 0.f;
#pragma unroll
    for (int ks = 0; ks < 2; ++ks) {
        bf16x8 af[4], bfr[4];
#pragma unroll
        for (int i = 0; i < 4; ++i)
            af[i] = __builtin_bit_cast(bf16x8,
                *(const s16x8*)&SH[(wr * 64 + i * 16 + lm) * 136 + wc * 64 + ks * 32 + quad * 8]);
#pragma unroll
        for (int jf = 0; jf < 4; ++jf)
            bfr[jf] = __builtin_bit_cast(bf16x8,
                *(const s16x8*)&Rs[(jf * 16 + lm) * 64 + (((ks * 4 + quad) ^ (lm & 7)) << 3)]);
#pragma unroll
        for (int i = 0; i < 4; ++i)
#pragma unroll
            for (int jf = 0; jf < 4; ++jf)
                acc2[i][jf] = __builtin_amdgcn_mfma_f32_16x16x32_bf16(af[i], bfr[jf], acc2[i][jf], 0, 0, 0);
    }
#pragma unroll
    for (int i = 0; i < 4; ++i)
#pragma unroll
        for (int jf = 0; jf < 4; ++jf) {
            int j = jf * 16 + lm;
            float4 dv = *(const float4*)&Dt[j * 384 + m0 + wr * 64 + i * 16 + quad * 4];
            acc2[i][jf][0] *= dv.x; acc2[i][jf][1] *= dv.y;
            acc2[i][jf][2] *= dv.z; acc2[i][jf][3] *= dv.w;
        }
    // Y -> Ep (quadrant-local overwrite; this warp's stage-1 reads are done)
#pragma unroll
    for (int i = 0; i < 4; ++i)
#pragma unroll
        for (int jf = 0; jf < 4; ++jf)
#pragma unroll
            for (int r = 0; r < 4; ++r)
                SH[(wr * 64 + i * 16 + quad * 4 + r) * 136 + wc * 64 + jf * 16 + lm] =
                    f2b(acc2[i][jf][r]);

    // ---- stage 2: T = Y x R (1/64 already folded into Dt). Quadrant-local.
    f32x4 acc3[4][4];
#pragma unroll
    for (int i = 0; i < 4; ++i)
#pragma unroll
        for (int j = 0; j < 4; ++j) acc3[i][j] = 0.f;
#pragma unroll
    for (int ks = 0; ks < 2; ++ks) {
        bf16x8 af[4], bfr[4];
#pragma unroll
        for (int i = 0; i < 4; ++i)
            af[i] = __builtin_bit_cast(bf16x8,
                *(const s16x8*)&SH[(wr * 64 + i * 16 + lm) * 136 + wc * 64 + ks * 32 + quad * 8]);
#pragma unroll
        for (int uf = 0; uf < 4; ++uf)
            bfr[uf] = __builtin_bit_cast(bf16x8,
                *(const s16x8*)&Rs[(uf * 16 + lm) * 64 + (((ks * 4 + quad) ^ (lm & 7)) << 3)]);
#pragma unroll
        for (int i = 0; i < 4; ++i)
#pragma unroll
            for (int uf = 0; uf < 4; ++uf)
                acc3[i][uf] = __builtin_amdgcn_mfma_f32_16x16x32_bf16(af[i], bfr[uf], acc3[i][uf], 0, 0, 0);
    }
    // T tile -> Ep (quadrant-local overwrite)
#pragma unroll
    for (int i = 0; i < 4; ++i)
#pragma unroll
        for (int uf = 0; uf < 4; ++uf)
#pragma unroll
            for (int r = 0; r < 4; ++r)
                SH[(wr * 64 + i * 16 + quad * 4 + r) * 136 + wc * 64 + uf * 16 + lm] =
                    f2b(acc3[i][uf][r]);
    __syncthreads();   // ONE barrier: global write-out reads all rows
    // patch-major write: T[b][ch][pid][uv]; lanes 0..15 cover 256B contiguous
    int pid0 = (h0 >> 3) * 32 + (w0 >> 3);
#pragma unroll
    for (int kq = 0; kq < 8; ++kq) {
        int idx = kq * 256 + tid;
        int row = idx >> 4, seg = idx & 15;
        s16x8 vv = *(const s16x8*)&SH[row * 136 + seg * 8];
        *(s16x8*)&T[(((size_t)(b * HID + m0 + row)) << 16) + (pid0 << 6) + seg * 8] = vv;
    }
}

// ---------------------------------------------------------------------------
// Fused depthwise 3x3 + gelu-gate + transpose: T PATCH-MAJOR -> Gt k-blocked
// Gt: [b][kseg=24][hw][8ch]. 8 channel-pairs per block, 64x16 spatial tile.
// ---------------------------------------------------------------------------
__global__ __launch_bounds__(256) void k_dwgt(const short* __restrict__ Y,
                                              const float* __restrict__ Wdw,
                                              short* __restrict__ Gt) {
    int bz = blockIdx.z;                 // b*24 + cg
    int b  = bz / 24;
    int cg = bz % 24;
    int c0 = cg * 8;
    int h0 = blockIdx.y * 16, w0 = blockIdx.x * 64;
    __shared__ __align__(16) short S[16][18][80];   // 46080 B
    __shared__ float sw[16][9];
    int tid = threadIdx.x;
    if (tid < 144) {
        int p = tid / 9, j = tid % 9;
        int ch = (p < 8) ? (c0 + p) : (c0 + p - 8 + 192);
        sw[p][j] = Wdw[ch * 9 + j];
    }
    for (int t = tid; t < 2880; t += 256) {
        int v = t % 10, r = (t / 10) % 18, p = t / 180;
        int gh = h0 + r - 1;
        int gw = w0 + v * 8 - 8;
        int ch = (p < 8) ? (c0 + p) : (c0 + p - 8 + 192);
        s16x8 val = {0, 0, 0, 0, 0, 0, 0, 0};
        if (gh >= 0 && gh < 256 && gw >= 0 && gw <= 248) {
            int pid = ((gh >> 3) << 5) + (gw >> 3);
            val = *(const s16x8*)&Y[((size_t)(b * HID + ch) << 16) + (pid << 6) + ((gh & 7) << 3)];
        }
        *(s16x8*)&S[p][r][v * 8] = val;
    }
    __syncthreads();
    s16x8 ov[4];
#pragma unroll
    for (int it = 0; it < 4; ++it) {
        int idx = it * 256 + tid;
        int p = idx >> 7, run = idx & 127;
        int r = run >> 3, c8 = (run & 7) * 8;
        float z1[8], z2[8];
#pragma unroll
        for (int k = 0; k < 8; ++k) { z1[k] = 0.f; z2[k] = 0.f; }
#pragma unroll
        for (int i = 0; i < 3; ++i) {
            {
                s16x4 wv[4];
#pragma unroll
                for (int q = 0; q < 4; ++q) wv[q] = *(const s16x4*)&S[p][r + i][c8 + 4 + q * 4];
                float fv[10];
#pragma unroll
                for (int q = 0; q < 10; ++q) fv[q] = b2f(wv[(q + 3) >> 2][(q + 3) & 3]);
#pragma unroll
                for (int j = 0; j < 3; ++j) {
                    float wgt = sw[p][i * 3 + j];
#pragma unroll
                    for (int k = 0; k < 8; ++k) z1[k] += fv[k + j] * wgt;
                }
            }
            {
                s16x4 wv[4];
#pragma unroll
                for (int q = 0; q < 4; ++q) wv[q] = *(const s16x4*)&S[p + 8][r + i][c8 + 4 + q * 4];
                float fv[10];
#pragma unroll
                for (int q = 0; q < 10; ++q) fv[q] = b2f(wv[(q + 3) >> 2][(q + 3) & 3]);
#pragma unroll
                for (int j = 0; j < 3; ++j) {
                    float wgt = sw[p + 8][i * 3 + j];
#pragma unroll
                    for (int k = 0; k < 8; ++k) z2[k] += fv[k + j] * wgt;
                }
            }
        }
#pragma unroll
        for (int k = 0; k < 8; ++k) {
            float g = 0.5f * z1[k] * (1.f + erff(z1[k] * 0.70710678118654752f));
            ov[it][k] = f2b(g * z2[k]);
        }
    }
    __syncthreads();
    short* Ob = (short*)S;
#pragma unroll
    for (int it = 0; it < 4; ++it) {
        int idx = it * 256 + tid;
        int p = idx >> 7, run = idx & 127;
        int pos = (run >> 3) * 64 + (run & 7) * 8;
#pragma unroll
        for (int k = 0; k < 8; ++k)
            Ob[(pos + k) * 9 + p] = ov[it][k];
    }
    __syncthreads();
    short* Gb = Gt + (((size_t)(b * 24 + cg)) << 16) * 8;
#pragma unroll
    for (int it = 0; it < 4; ++it) {
        int pos = it * 256 + tid;
        int r = pos >> 6, cl = pos & 63;
        s16x8 v;
#pragma unroll
        for (int k = 0; k < 8; ++k) v[k] = Ob[pos * 9 + k];
        *(s16x8*)&Gb[(size_t)(((h0 + r) << 8) + w0 + cl) * 8] = v;
    }
}

// ---------------------------------------------------------------------------
// MFMA bf16 GEMM2: C[z][m][n] = sum_k A[m][k] * Gt_blk[z][k/8][n][k%8]
// Grid x = 1536 flattened (512 n x 3 m), m fastest, XCD-chunk remapped.
// ---------------------------------------------------------------------------
__global__ __launch_bounds__(256) void k_gemm_bf16(const short* __restrict__ A,
                                                   const short* __restrict__ Bt,
                                                   float* __restrict__ C,
                                                   int N, int K) {
    __shared__ __align__(16) short As[128 * 32];
    __shared__ __align__(16) short Bs[128 * 32];
    const short* Bz = Bt + (size_t)blockIdx.z * (size_t)N * K;
    float* Cz = C + (size_t)blockIdx.z * (size_t)384 * N;
    int d = blockIdx.x;
    int wg = (d & 7) * 192 + (d >> 3);     // bijective XCD chunk remap
    int m0 = (wg % 3) * 128;
    int n0 = (wg / 3) * 128;
    int tid = threadIdx.x;
    int lane = tid & 63, w = tid >> 6;
    int wr = w >> 1, wc = w & 1;
    int lm = lane & 15, quad = lane >> 4;

    f32x4 acc[4][4];
#pragma unroll
    for (int i = 0; i < 4; ++i)
#pragma unroll
        for (int j = 0; j < 4; ++j) acc[i][j] = 0.f;

    int srow = tid >> 2, sseg = tid & 3;
    for (int k0 = 0; k0 < K; k0 += 32) {
        gl_lds16(A + (size_t)(m0 + srow) * K + k0 + sseg * 8, As + tid * 8);
        gl_lds16(A + (size_t)(m0 + 64 + srow) * K + k0 + sseg * 8, As + (tid + 256) * 8);
        gl_lds16(Bz + ((size_t)((k0 >> 3) + sseg) * HW + n0 + srow) * 8, Bs + tid * 8);
        gl_lds16(Bz + ((size_t)((k0 >> 3) + sseg) * HW + n0 + 64 + srow) * 8, Bs + (tid + 256) * 8);
        __syncthreads();
        bf16x8 af[4], bfr[4];
#pragma unroll
        for (int i = 0; i < 4; ++i)
            af[i] = __builtin_bit_cast(bf16x8, *(const s16x8*)&As[(wr * 64 + i * 16 + lm) * 32 + quad * 8]);
#pragma unroll
        for (int j = 0; j < 4; ++j)
            bfr[j] = __builtin_bit_cast(bf16x8, *(const s16x8*)&Bs[(wc * 64 + j * 16 + lm) * 32 + quad * 8]);
#pragma unroll
        for (int i = 0; i < 4; ++i)
#pragma unroll
            for (int j = 0; j < 4; ++j)
                acc[i][j] = __builtin_amdgcn_mfma_f32_16x16x32_bf16(af[i], bfr[j], acc[i][j], 0, 0, 0);
        __syncthreads();
    }
#pragma unroll
    for (int i = 0; i < 4; ++i) {
        int r0 = m0 + wr * 64 + i * 16 + quad * 4;
#pragma unroll
        for (int j = 0; j < 4; ++j) {
            int cidx = n0 + wc * 64 + j * 16 + lm;
#pragma unroll
            for (int r = 0; r < 4; ++r)
                Cz[(size_t)(r0 + r) * N + cidx] = acc[i][j][r];
        }
    }
}

// ---------------------------------------------------------------------------
extern "C" void kernel_launch(void* const* d_in, const int* in_sizes, int n_in,
                              void* d_out, int out_size, void* d_ws, size_t ws_size,
                              hipStream_t stream) {
    const float* x     = (const float*)d_in[0];
    const float* ff    = (const float*)d_in[1];
    const float* w_in  = (const float*)d_in[2];
    const float* w_dw  = (const float*)d_in[3];
    const float* w_out = (const float*)d_in[4];
    float* out = (float*)d_out;

    char* ws = (char*)d_ws;
    float* Dt   = (float*)ws;                                    // 98304 B
    short* wbin = (short*)(ws + 98304);                          // 294912 B
    short* wbout = (short*)(ws + 393216);                        // 147456 B
    short* Rbuf = (short*)(ws + 540672);                         // 8192 B
    short* bufA = (short*)(ws + 548864);                         // 100663296 B: Xt, then Gt
    short* bufB = (short*)(ws + 548864 + (size_t)100663296);     // 100663296 B: T (patch-major)
    short* Gt = bufA;

    k_prep<<<976, 256, 0, stream>>>(w_in, w_out, ff, wbin, wbout, Dt, Rbuf);
    k_cvtx<<<dim3(HW / 64, DIM / 64, BB), 256, 0, stream>>>(x, bufA);

    // fused GEMM1 + Hartley-domain circular conv -> T bf16 patch-major (bufB)
    k_gemm1c<<<dim3(1536, 1, BB), 256, 0, stream>>>(wbin, bufA, Rbuf, Dt, bufB);

    // fused depthwise 3x3 + gelu-gate + transpose -> Gt k-blocked (bufA; Xt dead)
    k_dwgt<<<dim3(4, 16, BB * 24), 256, 0, stream>>>(bufB, w_dw, Gt);

    // GEMM2: out = w_out @ g  (M=384, N=65536/batch, K=192)
    k_gemm_bf16<<<dim3(1536, 1, BB), 256, 0, stream>>>(wbout, Gt, out, HW, 192);
}

// Round 6
// 572.554 us; speedup vs baseline: 1.0472x; 1.0229x over previous
//
#include <hip/hip_runtime.h>
#include <hip/hip_bf16.h>
#include <math.h>

#define BB 2
#define DIM 384
#define HID 384
#define HW 65536

typedef short s16x8 __attribute__((ext_vector_type(8)));
typedef short s16x4 __attribute__((ext_vector_type(4)));
typedef __bf16 bf16x8 __attribute__((ext_vector_type(8)));
typedef float f32x4 __attribute__((ext_vector_type(4)));

__device__ inline short f2b(float f) {
    __hip_bfloat16 h = __float2bfloat16(f);
    return __builtin_bit_cast(short, h);
}
__device__ inline float b2f(short s) {
    return __bfloat162float(__builtin_bit_cast(__hip_bfloat16, s));
}

__device__ inline void gl_lds16(const short* g, short* l) {
    __builtin_amdgcn_global_load_lds(
        (const __attribute__((address_space(1))) unsigned int*)g,
        (__attribute__((address_space(3))) unsigned int*)l, 16, 0, 0);
}

// ---------------------------------------------------------------------------
// One prep kernel: wbin (147456), wbout (73728), Dt (24576), Rb (4096).
// ---------------------------------------------------------------------------
__global__ void k_prep(const float* __restrict__ w_in, const float* __restrict__ w_out,
                       const float* __restrict__ F,
                       short* __restrict__ wbin, short* __restrict__ wbout,
                       float* __restrict__ Dt, short* __restrict__ Rb) {
    int i = blockIdx.x * 256 + threadIdx.x;
    if (i < 147456) { wbin[i] = f2b(w_in[i]); return; }
    i -= 147456;
    if (i < 73728) { wbout[i] = f2b(w_out[i]); return; }
    i -= 73728;
    if (i < 24576) {
        // Dt[j][c]: Hartley eigenvalue of per-channel filter (incl. 1/64)
        int c = i >> 6, j = i & 63;
        int a = j >> 3, q = j & 7;
        float d;
        if (q >= 1 && q <= 3)
            d = F[c * 40 + a * 5 + q];
        else if (q >= 5)
            d = F[c * 40 + ((8 - a) & 7) * 5 + (8 - q)];
        else
            d = 0.5f * (F[c * 40 + a * 5 + q] + F[c * 40 + ((8 - a) & 7) * 5 + q]);
        Dt[j * 384 + c] = d * (1.f / 64.f);
        return;
    }
    i -= 24576;
    if (i < 4096) {
        // R: 64x64 2D-Hartley (cas) basis, bf16. Symmetric, R*R = 64*I.
        int j = i >> 6, k = i & 63;
        const float cas[8] = {1.f, 1.41421356237f, 1.f, 0.f, -1.f, -1.41421356237f, -1.f, 0.f};
        int t = ((j >> 3) * (k >> 3) + (j & 7) * (k & 7)) & 7;
        Rb[i] = f2b(cas[t]);
    }
}

// ---------------------------------------------------------------------------
// Fused cvt+GEMM1+Hartley circular conv. Reads x fp32 DIRECTLY (no Xt):
// per k-chunk each thread loads 16 contiguous fp32 of one (channel,row),
// converts in-register, scatter-writes bf16 into Bs[pos][c] (conflict-free).
// 2-phase double-buffered (issue-early / write-late). Epilogue: T=R*D*R on
// the acc tile, quadrant-local, single barrier, patch-major T output.
// ---------------------------------------------------------------------------
__global__ __launch_bounds__(256) void k_gemm1c(const short* __restrict__ A,
                                                const float* __restrict__ X,
                                                const short* __restrict__ Rb,
                                                const float* __restrict__ Dt,
                                                short* __restrict__ T) {
    // shorts: [0..4095] As0 | [4096..8191] Bs0 | [8192..12287] As1 | [12288..16383] Bs1
    // Ep (epilogue) aliases [0..17407]; Rs at +17408.
    __shared__ __align__(16) short SH[17408 + 4096];
    short* Rs = SH + 17408;
    int d = blockIdx.x;
    int wg = (d & 7) * 192 + (d >> 3);     // bijective XCD chunk remap (1536 % 8 == 0)
    int m0 = (wg % 3) * 128;
    int tx = wg / 3;
    int h0 = (tx >> 4) * 8;
    int w0 = (tx & 15) * 16;
    int b  = blockIdx.z;
    int tid = threadIdx.x;
    int lane = tid & 63, w = tid >> 6;
    int wr = w >> 1, wc = w & 1;
    int lm = lane & 15, quad = lane >> 4;

    // stage Hartley basis R (swizzled source -> linear LDS dest)
    {
        int j0 = tid >> 3, kb0 = tid & 7;
        gl_lds16(Rb + j0 * 64 + ((kb0 ^ (j0 & 7)) << 3), Rs + tid * 8);
        int t2 = tid + 256;
        int j1 = t2 >> 3, kb1 = t2 & 7;
        gl_lds16(Rb + j1 * 64 + ((kb1 ^ (j1 & 7)) << 3), Rs + t2 * 8);
    }

    int srow = tid >> 2, sseg = tid & 3;        // A staging coords
    int cB = tid & 31, uB = tid >> 5;           // B staging coords (channel, h-row)
    const float* xp = X + (((size_t)(b * DIM + cB)) << 16) + ((h0 + uB) << 8) + w0;
    int bwb = uB * 256 + cB;                    // Bs offset base (+pat*2048 + v*32)

    f32x4 acc[4][4];
#pragma unroll
    for (int i = 0; i < 4; ++i)
#pragma unroll
        for (int j = 0; j < 4; ++j) acc[i][j] = 0.f;

    float4 rB[4];
    // prologue: chunk 0 -> buf0
#pragma unroll
    for (int q = 0; q < 4; ++q) rB[q] = ((const float4*)xp)[q];
    gl_lds16(A + (size_t)(m0 + srow) * DIM + sseg * 8, SH + tid * 8);
    gl_lds16(A + (size_t)(m0 + 64 + srow) * DIM + sseg * 8, SH + (tid + 256) * 8);
    {
        short* p = SH + 4096 + bwb;
        p[0]    = f2b(rB[0].x); p[32]   = f2b(rB[0].y); p[64]   = f2b(rB[0].z); p[96]   = f2b(rB[0].w);
        p[128]  = f2b(rB[1].x); p[160]  = f2b(rB[1].y); p[192]  = f2b(rB[1].z); p[224]  = f2b(rB[1].w);
        p[2048] = f2b(rB[2].x); p[2080] = f2b(rB[2].y); p[2112] = f2b(rB[2].z); p[2144] = f2b(rB[2].w);
        p[2176] = f2b(rB[3].x); p[2208] = f2b(rB[3].y); p[2240] = f2b(rB[3].z); p[2272] = f2b(rB[3].w);
    }
    __syncthreads();

    int cur = 0;
#pragma unroll 2
    for (int kc = 0; kc < 12; ++kc) {
        short* nA = SH + ((cur ^ 1) ? 8192 : 0);
        short* nB = SH + ((cur ^ 1) ? 12288 : 4096);
        if (kc < 11) {
            // issue-early: next chunk's global loads
            const float* xq = xp + ((size_t)(kc + 1) << 21);   // +32 channels
#pragma unroll
            for (int q = 0; q < 4; ++q) rB[q] = ((const float4*)xq)[q];
            gl_lds16(A + (size_t)(m0 + srow) * DIM + (kc + 1) * 32 + sseg * 8, nA + tid * 8);
            gl_lds16(A + (size_t)(m0 + 64 + srow) * DIM + (kc + 1) * 32 + sseg * 8, nA + (tid + 256) * 8);
        }
        // MFMA on current buffer
        {
            const short* Ar = SH + (cur ? 8192 : 0);
            const short* Br = SH + (cur ? 12288 : 4096);
            bf16x8 af[4], bfr[4];
#pragma unroll
            for (int i = 0; i < 4; ++i)
                af[i] = __builtin_bit_cast(bf16x8, *(const s16x8*)&Ar[(wr * 64 + i * 16 + lm) * 32 + quad * 8]);
#pragma unroll
            for (int j = 0; j < 4; ++j)
                bfr[j] = __builtin_bit_cast(bf16x8, *(const s16x8*)&Br[(wc * 64 + j * 16 + lm) * 32 + quad * 8]);
#pragma unroll
            for (int i = 0; i < 4; ++i)
#pragma unroll
                for (int j = 0; j < 4; ++j)
                    acc[i][j] = __builtin_amdgcn_mfma_f32_16x16x32_bf16(af[i], bfr[j], acc[i][j], 0, 0, 0);
        }
        if (kc < 11) {
            // write-late: convert + scatter into next B buffer (conflict-free b16)
            short* p = nB + bwb;
            p[0]    = f2b(rB[0].x); p[32]   = f2b(rB[0].y); p[64]   = f2b(rB[0].z); p[96]   = f2b(rB[0].w);
            p[128]  = f2b(rB[1].x); p[160]  = f2b(rB[1].y); p[192]  = f2b(rB[1].z); p[224]  = f2b(rB[1].w);
            p[2048] = f2b(rB[2].x); p[2080] = f2b(rB[2].y); p[2112] = f2b(rB[2].z); p[2144] = f2b(rB[2].w);
            p[2176] = f2b(rB[3].x); p[2208] = f2b(rB[3].y); p[2240] = f2b(rB[3].z); p[2272] = f2b(rB[3].w);
        }
        __syncthreads();
        cur ^= 1;
    }

    // ---- E tile (bf16) -> Ep[ch][pat*64+uv], stride 136. Quadrant-local.
#pragma unroll
    for (int i = 0; i < 4; ++i)
#pragma unroll
        for (int j = 0; j < 4; ++j)
#pragma unroll
            for (int r = 0; r < 4; ++r)
                SH[(wr * 64 + i * 16 + quad * 4 + r) * 136 + wc * 64 + j * 16 + lm] =
                    f2b(acc[i][j][r]);

    // ---- stage 1: Y = E x R (contract uv within pat=wc), scale by Dt[j][ch]
    f32x4 acc2[4][4];
#pragma unroll
    for (int i = 0; i < 4; ++i)
#pragma unroll
        for (int j = 0; j < 4; ++j) acc2[i][j] = 0.f;
#pragma unroll
    for (int ks = 0; ks < 2; ++ks) {
        bf16x8 af[4], bfr[4];
#pragma unroll
        for (int i = 0; i < 4; ++i)
            af[i] = __builtin_bit_cast(bf16x8,
                *(const s16x8*)&SH[(wr * 64 + i * 16 + lm) * 136 + wc * 64 + ks * 32 + quad * 8]);
#pragma unroll
        for (int jf = 0; jf < 4; ++jf)
            bfr[jf] = __builtin_bit_cast(bf16x8,
                *(const s16x8*)&Rs[(jf * 16 + lm) * 64 + (((ks * 4 + quad) ^ (lm & 7)) << 3)]);
#pragma unroll
        for (int i = 0; i < 4; ++i)
#pragma unroll
            for (int jf = 0; jf < 4; ++jf)
                acc2[i][jf] = __builtin_amdgcn_mfma_f32_16x16x32_bf16(af[i], bfr[jf], acc2[i][jf], 0, 0, 0);
    }
#pragma unroll
    for (int i = 0; i < 4; ++i)
#pragma unroll
        for (int jf = 0; jf < 4; ++jf) {
            int j = jf * 16 + lm;
            float4 dv = *(const float4*)&Dt[j * 384 + m0 + wr * 64 + i * 16 + quad * 4];
            acc2[i][jf][0] *= dv.x; acc2[i][jf][1] *= dv.y;
            acc2[i][jf][2] *= dv.z; acc2[i][jf][3] *= dv.w;
        }
#pragma unroll
    for (int i = 0; i < 4; ++i)
#pragma unroll
        for (int jf = 0; jf < 4; ++jf)
#pragma unroll
            for (int r = 0; r < 4; ++r)
                SH[(wr * 64 + i * 16 + quad * 4 + r) * 136 + wc * 64 + jf * 16 + lm] =
                    f2b(acc2[i][jf][r]);

    // ---- stage 2: T = Y x R (1/64 already folded into Dt). Quadrant-local.
    f32x4 acc3[4][4];
#pragma unroll
    for (int i = 0; i < 4; ++i)
#pragma unroll
        for (int j = 0; j < 4; ++j) acc3[i][j] = 0.f;
#pragma unroll
    for (int ks = 0; ks < 2; ++ks) {
        bf16x8 af[4], bfr[4];
#pragma unroll
        for (int i = 0; i < 4; ++i)
            af[i] = __builtin_bit_cast(bf16x8,
                *(const s16x8*)&SH[(wr * 64 + i * 16 + lm) * 136 + wc * 64 + ks * 32 + quad * 8]);
#pragma unroll
        for (int uf = 0; uf < 4; ++uf)
            bfr[uf] = __builtin_bit_cast(bf16x8,
                *(const s16x8*)&Rs[(uf * 16 + lm) * 64 + (((ks * 4 + quad) ^ (lm & 7)) << 3)]);
#pragma unroll
        for (int i = 0; i < 4; ++i)
#pragma unroll
            for (int uf = 0; uf < 4; ++uf)
                acc3[i][uf] = __builtin_amdgcn_mfma_f32_16x16x32_bf16(af[i], bfr[uf], acc3[i][uf], 0, 0, 0);
    }
#pragma unroll
    for (int i = 0; i < 4; ++i)
#pragma unroll
        for (int uf = 0; uf < 4; ++uf)
#pragma unroll
            for (int r = 0; r < 4; ++r)
                SH[(wr * 64 + i * 16 + quad * 4 + r) * 136 + wc * 64 + uf * 16 + lm] =
                    f2b(acc3[i][uf][r]);
    __syncthreads();   // ONE barrier: global write-out reads all rows
    // patch-major write: T[b][ch][pid][uv]; lanes 0..15 cover 256B contiguous
    int pid0 = (h0 >> 3) * 32 + (w0 >> 3);
#pragma unroll
    for (int kq = 0; kq < 8; ++kq) {
        int idx = kq * 256 + tid;
        int row = idx >> 4, seg = idx & 15;
        s16x8 vv = *(const s16x8*)&SH[row * 136 + seg * 8];
        *(s16x8*)&T[(((size_t)(b * HID + m0 + row)) << 16) + (pid0 << 6) + seg * 8] = vv;
    }
}

// ---------------------------------------------------------------------------
// Fused depthwise 3x3 + gelu-gate + transpose: T PATCH-MAJOR -> Gt k-blocked
// Gt: [b][kseg=24][hw][8ch]. 8 channel-pairs per block, 64x16 spatial tile.
// ---------------------------------------------------------------------------
__global__ __launch_bounds__(256) void k_dwgt(const short* __restrict__ Y,
                                              const float* __restrict__ Wdw,
                                              short* __restrict__ Gt) {
    int bz = blockIdx.z;                 // b*24 + cg
    int b  = bz / 24;
    int cg = bz % 24;
    int c0 = cg * 8;
    int h0 = blockIdx.y * 16, w0 = blockIdx.x * 64;
    __shared__ __align__(16) short S[16][18][80];   // 46080 B
    __shared__ float sw[16][9];
    int tid = threadIdx.x;
    if (tid < 144) {
        int p = tid / 9, j = tid % 9;
        int ch = (p < 8) ? (c0 + p) : (c0 + p - 8 + 192);
        sw[p][j] = Wdw[ch * 9 + j];
    }
    for (int t = tid; t < 2880; t += 256) {
        int v = t % 10, r = (t / 10) % 18, p = t / 180;
        int gh = h0 + r - 1;
        int gw = w0 + v * 8 - 8;
        int ch = (p < 8) ? (c0 + p) : (c0 + p - 8 + 192);
        s16x8 val = {0, 0, 0, 0, 0, 0, 0, 0};
        if (gh >= 0 && gh < 256 && gw >= 0 && gw <= 248) {
            int pid = ((gh >> 3) << 5) + (gw >> 3);
            val = *(const s16x8*)&Y[((size_t)(b * HID + ch) << 16) + (pid << 6) + ((gh & 7) << 3)];
        }
        *(s16x8*)&S[p][r][v * 8] = val;
    }
    __syncthreads();
    s16x8 ov[4];
#pragma unroll
    for (int it = 0; it < 4; ++it) {
        int idx = it * 256 + tid;
        int p = idx >> 7, run = idx & 127;
        int r = run >> 3, c8 = (run & 7) * 8;
        float z1[8], z2[8];
#pragma unroll
        for (int k = 0; k < 8; ++k) { z1[k] = 0.f; z2[k] = 0.f; }
#pragma unroll
        for (int i = 0; i < 3; ++i) {
            {
                s16x4 wv[4];
#pragma unroll
                for (int q = 0; q < 4; ++q) wv[q] = *(const s16x4*)&S[p][r + i][c8 + 4 + q * 4];
                float fv[10];
#pragma unroll
                for (int q = 0; q < 10; ++q) fv[q] = b2f(wv[(q + 3) >> 2][(q + 3) & 3]);
#pragma unroll
                for (int j = 0; j < 3; ++j) {
                    float wgt = sw[p][i * 3 + j];
#pragma unroll
                    for (int k = 0; k < 8; ++k) z1[k] += fv[k + j] * wgt;
                }
            }
            {
                s16x4 wv[4];
#pragma unroll
                for (int q = 0; q < 4; ++q) wv[q] = *(const s16x4*)&S[p + 8][r + i][c8 + 4 + q * 4];
                float fv[10];
#pragma unroll
                for (int q = 0; q < 10; ++q) fv[q] = b2f(wv[(q + 3) >> 2][(q + 3) & 3]);
#pragma unroll
                for (int j = 0; j < 3; ++j) {
                    float wgt = sw[p + 8][i * 3 + j];
#pragma unroll
                    for (int k = 0; k < 8; ++k) z2[k] += fv[k + j] * wgt;
                }
            }
        }
#pragma unroll
        for (int k = 0; k < 8; ++k) {
            float g = 0.5f * z1[k] * (1.f + erff(z1[k] * 0.70710678118654752f));
            ov[it][k] = f2b(g * z2[k]);
        }
    }
    __syncthreads();
    short* Ob = (short*)S;
#pragma unroll
    for (int it = 0; it < 4; ++it) {
        int idx = it * 256 + tid;
        int p = idx >> 7, run = idx & 127;
        int pos = (run >> 3) * 64 + (run & 7) * 8;
#pragma unroll
        for (int k = 0; k < 8; ++k)
            Ob[(pos + k) * 9 + p] = ov[it][k];
    }
    __syncthreads();
    short* Gb = Gt + (((size_t)(b * 24 + cg)) << 16) * 8;
#pragma unroll
    for (int it = 0; it < 4; ++it) {
        int pos = it * 256 + tid;
        int r = pos >> 6, cl = pos & 63;
        s16x8 v;
#pragma unroll
        for (int k = 0; k < 8; ++k) v[k] = Ob[pos * 9 + k];
        *(s16x8*)&Gb[(size_t)(((h0 + r) << 8) + w0 + cl) * 8] = v;
    }
}

// ---------------------------------------------------------------------------
// MFMA bf16 GEMM2 (2-phase dbuf): C[z][m][n] = sum_k A[m][k]*Gt[z][k/8][n][k%8]
// Grid x = 1536 flattened (512 n x 3 m), m fastest, XCD-chunk remapped.
// ---------------------------------------------------------------------------
__global__ __launch_bounds__(256) void k_gemm_bf16(const short* __restrict__ A,
                                                   const short* __restrict__ Bt,
                                                   float* __restrict__ C,
                                                   int N, int K) {
    // shorts: As0 [0..4095] | Bs0 [4096..8191] | As1 [8192..12287] | Bs1 [12288..16383]
    __shared__ __align__(16) short SH[16384];
    const short* Bz = Bt + (size_t)blockIdx.z * (size_t)N * K;
    float* Cz = C + (size_t)blockIdx.z * (size_t)384 * N;
    int d = blockIdx.x;
    int wg = (d & 7) * 192 + (d >> 3);     // bijective XCD chunk remap
    int m0 = (wg % 3) * 128;
    int n0 = (wg / 3) * 128;
    int tid = threadIdx.x;
    int lane = tid & 63, w = tid >> 6;
    int wr = w >> 1, wc = w & 1;
    int lm = lane & 15, quad = lane >> 4;

    f32x4 acc[4][4];
#pragma unroll
    for (int i = 0; i < 4; ++i)
#pragma unroll
        for (int j = 0; j < 4; ++j) acc[i][j] = 0.f;

    int srow = tid >> 2, sseg = tid & 3;
    // prologue chunk 0 -> buf0
    gl_lds16(A + (size_t)(m0 + srow) * K + sseg * 8, SH + tid * 8);
    gl_lds16(A + (size_t)(m0 + 64 + srow) * K + sseg * 8, SH + (tid + 256) * 8);
    gl_lds16(Bz + ((size_t)sseg * HW + n0 + srow) * 8, SH + 4096 + tid * 8);
    gl_lds16(Bz + ((size_t)sseg * HW + n0 + 64 + srow) * 8, SH + 4096 + (tid + 256) * 8);
    __syncthreads();

    int cur = 0;
#pragma unroll 2
    for (int kc = 0; kc < 6; ++kc) {
        if (kc < 5) {
            short* nA = SH + ((cur ^ 1) ? 8192 : 0);
            short* nB = nA + 4096;
            int k0 = (kc + 1) * 32;
            gl_lds16(A + (size_t)(m0 + srow) * K + k0 + sseg * 8, nA + tid * 8);
            gl_lds16(A + (size_t)(m0 + 64 + srow) * K + k0 + sseg * 8, nA + (tid + 256) * 8);
            gl_lds16(Bz + ((size_t)((k0 >> 3) + sseg) * HW + n0 + srow) * 8, nB + tid * 8);
            gl_lds16(Bz + ((size_t)((k0 >> 3) + sseg) * HW + n0 + 64 + srow) * 8, nB + (tid + 256) * 8);
        }
        const short* Ar = SH + (cur ? 8192 : 0);
        const short* Br = Ar + 4096;
        bf16x8 af[4], bfr[4];
#pragma unroll
        for (int i = 0; i < 4; ++i)
            af[i] = __builtin_bit_cast(bf16x8, *(const s16x8*)&Ar[(wr * 64 + i * 16 + lm) * 32 + quad * 8]);
#pragma unroll
        for (int j = 0; j < 4; ++j)
            bfr[j] = __builtin_bit_cast(bf16x8, *(const s16x8*)&Br[(wc * 64 + j * 16 + lm) * 32 + quad * 8]);
#pragma unroll
        for (int i = 0; i < 4; ++i)
#pragma unroll
            for (int j = 0; j < 4; ++j)
                acc[i][j] = __builtin_amdgcn_mfma_f32_16x16x32_bf16(af[i], bfr[j], acc[i][j], 0, 0, 0);
        __syncthreads();
        cur ^= 1;
    }
#pragma unroll
    for (int i = 0; i < 4; ++i) {
        int r0 = m0 + wr * 64 + i * 16 + quad * 4;
#pragma unroll
        for (int j = 0; j < 4; ++j) {
            int cidx = n0 + wc * 64 + j * 16 + lm;
#pragma unroll
            for (int r = 0; r < 4; ++r)
                Cz[(size_t)(r0 + r) * N + cidx] = acc[i][j][r];
        }
    }
}

// ---------------------------------------------------------------------------
extern "C" void kernel_launch(void* const* d_in, const int* in_sizes, int n_in,
                              void* d_out, int out_size, void* d_ws, size_t ws_size,
                              hipStream_t stream) {
    const float* x     = (const float*)d_in[0];
    const float* ff    = (const float*)d_in[1];
    const float* w_in  = (const float*)d_in[2];
    const float* w_dw  = (const float*)d_in[3];
    const float* w_out = (const float*)d_in[4];
    float* out = (float*)d_out;

    char* ws = (char*)d_ws;
    float* Dt   = (float*)ws;                                    // 98304 B
    short* wbin = (short*)(ws + 98304);                          // 294912 B
    short* wbout = (short*)(ws + 393216);                        // 147456 B
    short* Rbuf = (short*)(ws + 540672);                         // 8192 B
    short* Gt   = (short*)(ws + 548864);                         // 50331648 B (k-blocked)
    short* Tbuf = (short*)(ws + 548864 + (size_t)100663296);     // 100663296 B (patch-major)

    k_prep<<<976, 256, 0, stream>>>(w_in, w_out, ff, wbin, wbout, Dt, Rbuf);

    // fused cvt + GEMM1 + Hartley circular conv -> T bf16 patch-major
    k_gemm1c<<<dim3(1536, 1, BB), 256, 0, stream>>>(wbin, x, Rbuf, Dt, Tbuf);

    // fused depthwise 3x3 + gelu-gate + transpose -> Gt k-blocked
    k_dwgt<<<dim3(4, 16, BB * 24), 256, 0, stream>>>(Tbuf, w_dw, Gt);

    // GEMM2: out = w_out @ g  (M=384, N=65536/batch, K=192)
    k_gemm_bf16<<<dim3(1536, 1, BB), 256, 0, stream>>>(wbout, Gt, out, HW, 192);
}